// Round 6
// baseline (245.942 us; speedup 1.0000x reference)
//
#include <hip/hip_runtime.h>
#include <stdint.h>

#define BATCH 2
#define NPTS  4096
#define KNBR  32
#define TOKC  128

typedef _Float16 half8 __attribute__((ext_vector_type(8)));
typedef _Float16 half4 __attribute__((ext_vector_type(4)));
typedef float    f32x4 __attribute__((ext_vector_type(4)));

// ---------------- workspace layout (bytes) ----------------
// idx : int [2*4096*32] @ 0 ; Fh @ 1MB ; Ah @ 3MB ; gmax @ 5MB
#define OFF_FH   (1u << 20)
#define OFF_AH   (3u << 20)
#define OFF_GMAX (5u << 20)

__device__ __forceinline__ unsigned int fkey(float f) {
    unsigned int u = __float_as_uint(f);
    return (u & 0x80000000u) ? ~u : (u | 0x80000000u);
}
__device__ __forceinline__ float funkey(unsigned int k) {
    return __uint_as_float((k & 0x80000000u) ? (k ^ 0x80000000u) : ~k);
}

// ---------------- heterogeneous pre-pass: blocks 0..2047 = ball-query, 2048..2559 = MFMA prep ----------------
// Search and prep are independent; mixing roles in one grid co-schedules latency-bound
// search waves with MFMA-bound prep waves on the same CUs and saves a launch.
__global__ __launch_bounds__(256) void k_pre(const float* __restrict__ xyz,
                                             const float* __restrict__ feat,
                                             const float* __restrict__ W1,
                                             const float* __restrict__ b1,
                                             int* __restrict__ oidx,
                                             _Float16* __restrict__ Fh,
                                             _Float16* __restrict__ Ah) {
    __shared__ __align__(16) _Float16 inL[16][168];   // prep only: k 0..63 feat, 64..159 abs-pe, +8 pad
    const int t = threadIdx.x;
    const int w = t >> 6, lane = t & 63;

    if (blockIdx.x < 2048) {
        // ---- ball query: one wave per point, next-chunk prefetch (bit-exact vs numpy) ----
        int wave = blockIdx.x * 4 + w;
        int b = wave >> 12;
        int n = wave & (NPTS - 1);
        const float* xb = xyz + (size_t)b * NPTS * 3;
        float cx = xb[n * 3 + 0], cy = xb[n * 3 + 1], cz = xb[n * 3 + 2];
        const float R2 = 0.0256f;
        int cnt = 0;
        int first = 0;
        int* out = oidx + (size_t)wave * KNBR;
        float px = xb[lane * 3 + 0], py = xb[lane * 3 + 1], pz = xb[lane * 3 + 2];
        for (int base = 0; base < NPTS; base += 64) {
            #pragma clang fp contract(off)
            float dx = px - cx, dy = py - cy, dz = pz - cz;
            float d2 = (dx * dx + dy * dy) + dz * dz;   // same order as numpy, no fma
            bool hit = d2 <= R2;
            int jn = ((base + 64) & (NPTS - 1)) + lane;
            float nx = xb[jn * 3 + 0], ny = xb[jn * 3 + 1], nz = xb[jn * 3 + 2];
            unsigned long long m = __ballot(hit);
            if (cnt == 0 && m) first = base + (int)__builtin_ctzll(m);
            if (hit) {
                int pos = cnt + (int)__popcll(m & ((1ull << lane) - 1ull));
                if (pos < KNBR) out[pos] = base + lane;
            }
            cnt += (int)__popcll(m);
            if (cnt >= KNBR) break;
            px = nx; py = ny; pz = nz;
        }
        if (lane >= cnt && lane < KNBR) out[lane] = first;
        return;
    }

    // ---- prep: F[j] = feat@W1[0:64], A[n] = abs_pe@W1[91:187]+b1, via MFMA ----
    const int l15 = lane & 15, g = lane >> 4;
    const int g0 = (blockIdx.x - 2048) * 16;          // flat point base (b*N+n)

    half8 af[2][2];
    half8 ap[2][3];
    float4 b1v[2];
    #pragma unroll
    for (int rt = 0; rt < 2; rt++) {
        int c = 32 * w + 16 * rt + l15;
        #pragma unroll
        for (int kc = 0; kc < 2; kc++)
            #pragma unroll
            for (int j = 0; j < 8; j++)
                af[rt][kc][j] = (_Float16)W1[(kc * 32 + g * 8 + j) * TOKC + c];
        #pragma unroll
        for (int kc = 0; kc < 3; kc++)
            #pragma unroll
            for (int j = 0; j < 8; j++)
                ap[rt][kc][j] = (_Float16)W1[(91 + kc * 32 + g * 8 + j) * TOKC + c];
        b1v[rt] = *(const float4*)&b1[32 * w + 16 * rt + g * 4];
    }

    {
        float4 v = ((const float4*)(feat + (size_t)g0 * 64))[t];
        half4 hv = {(_Float16)v.x, (_Float16)v.y, (_Float16)v.z, (_Float16)v.w};
        *(half4*)&inL[t >> 4][(t & 15) * 4] = hv;
    }
    {
        int p = t >> 4, v0 = (t & 15) * 6;
        const float* xp = xyz + (size_t)(g0 + p) * 3;
        #pragma unroll
        for (int u = 0; u < 6; u++) {
            int d = v0 + u;
            int a = d >> 5, i = d & 31, fi = i & 15;
            float fr = __expf(-0.6140226914650789f * (float)fi);  // ln(1e4)/15
            float ang = xp[a] * fr;
            inL[p][64 + d] = (_Float16)((i < 16) ? __sinf(ang) : __cosf(ang));
        }
    }
    __syncthreads();

    f32x4 cF[2], cA[2];
    #pragma unroll
    for (int rt = 0; rt < 2; rt++) { f32x4 z = {0.f, 0.f, 0.f, 0.f}; cF[rt] = z; cA[rt] = z; }
    #pragma unroll
    for (int kc = 0; kc < 2; kc++) {
        half8 bx = *(const half8*)&inL[l15][kc * 32 + g * 8];
        cF[0] = __builtin_amdgcn_mfma_f32_16x16x32_f16(af[0][kc], bx, cF[0], 0, 0, 0);
        cF[1] = __builtin_amdgcn_mfma_f32_16x16x32_f16(af[1][kc], bx, cF[1], 0, 0, 0);
    }
    #pragma unroll
    for (int kc = 0; kc < 3; kc++) {
        half8 bx = *(const half8*)&inL[l15][64 + kc * 32 + g * 8];
        cA[0] = __builtin_amdgcn_mfma_f32_16x16x32_f16(ap[0][kc], bx, cA[0], 0, 0, 0);
        cA[1] = __builtin_amdgcn_mfma_f32_16x16x32_f16(ap[1][kc], bx, cA[1], 0, 0, 0);
    }

    size_t pbase = ((size_t)g0 + l15) * TOKC;
    #pragma unroll
    for (int rt = 0; rt < 2; rt++) {
        int ch0 = 32 * w + 16 * rt + g * 4;
        half4 fv, av;
        #pragma unroll
        for (int r = 0; r < 4; r++) {
            fv[r] = (_Float16)cF[rt][r];
            av[r] = (_Float16)(cA[rt][r] + b1v[rt][r]);
        }
        *(half4*)&Fh[pbase + ch0] = fv;
        *(half4*)&Ah[pbase + ch0] = av;
    }
}

// ---------------- main: 2048 blocks, one 4-point/128-pair tile each, fp16 MFMA both layers ----------------
__global__ __launch_bounds__(256, 2) void k_main(const float* __restrict__ xyz,
                                                 const float* __restrict__ W1,
                                                 const float* __restrict__ W2,
                                                 const int* __restrict__ idxw,
                                                 const _Float16* __restrict__ Fh,
                                                 const _Float16* __restrict__ Ah,
                                                 unsigned int* __restrict__ gmax) {
    __shared__ __align__(16) _Float16 xinL[128 * 40];   // [pair][k32+pad8]
    __shared__ __align__(16) _Float16 hfa[128 * 136];   // [pair][ch128+pad8]
    __shared__ __align__(16) _Float16 arowL[512];
    __shared__ int jidxL[128];

    const int t = threadIdx.x;
    const int w = t >> 6, lane = t & 63;
    const int l15 = lane & 15, g = lane >> 4;
    const int b = blockIdx.x >> 10;
    const int n0 = (blockIdx.x & 1023) * 4;
    const size_t gp0 = (size_t)b * NPTS + n0;
    const float* xb = xyz + (size_t)b * NPTS * 3;

    // stage idx + A-bias rows first (dependencies of the staging phase)
    if (t < 128) jidxL[t] = idxw[gp0 * KNBR + t];
    {
        const ushort* Ain = (const ushort*)(Ah + gp0 * TOKC);
        ((ushort*)arowL)[t]       = Ain[t];
        ((ushort*)arowL)[t + 256] = Ain[t + 256];
    }

    // persistent weight fragments (independent loads, hide under the barrier)
    half8 a1[2];
    half8 a2[2][4];
    #pragma unroll
    for (int rt = 0; rt < 2; rt++) {
        int c = 32 * w + 16 * rt + l15;
        #pragma unroll
        for (int j = 0; j < 8; j++) {
            int k = g * 8 + j;
            a1[rt][j] = (k < 27) ? (_Float16)W1[(64 + k) * TOKC + c] : (_Float16)0.f;
        }
        #pragma unroll
        for (int kc = 0; kc < 4; kc++)
            #pragma unroll
            for (int j = 0; j < 8; j++)
                a2[rt][kc][j] = (_Float16)W2[(kc * 32 + g * 8 + j) * TOKC + c];
    }
    __syncthreads();

    // --- stage xin (rel xyz + rel PE) and hfa = F[j] + A[n] ---
    const float FR[4] = {1.f, 0.0464158883f, 0.00215443469f, 1e-4f};
    if (t < 128) {
        int p = t, n = n0 + (p >> 5), j = jidxL[p];
        float rx = xb[j * 3 + 0] - xb[n * 3 + 0];
        float ry = xb[j * 3 + 1] - xb[n * 3 + 1];
        float rz = xb[j * 3 + 2] - xb[n * 3 + 2];
        float v[32];
        v[0] = rx; v[1] = ry; v[2] = rz;
        float r3[3] = {rx, ry, rz};
        #pragma unroll
        for (int a = 0; a < 3; a++)
            #pragma unroll
            for (int fi = 0; fi < 4; fi++) {
                float ang = r3[a] * FR[fi];
                v[3 + a * 8 + fi]     = __sinf(ang);
                v[3 + a * 8 + 4 + fi] = __cosf(ang);
            }
        #pragma unroll
        for (int i = 27; i < 32; i++) v[i] = 0.f;
        #pragma unroll
        for (int q = 0; q < 4; q++) {
            half8 hv;
            #pragma unroll
            for (int j2 = 0; j2 < 8; j2++) hv[j2] = (_Float16)v[q * 8 + j2];
            *(half8*)&xinL[p * 40 + q * 8] = hv;
        }
    }
    {
        int p = t >> 1, hh = t & 1;
        int j = jidxL[p];
        const half8* fr = (const half8*)(Fh + ((size_t)b * NPTS + j) * TOKC + hh * 64);
        const half8* ar = (const half8*)(arowL + (p >> 5) * TOKC + hh * 64);
        half8* dst = (half8*)(hfa + p * 136 + hh * 64);
        #pragma unroll
        for (int i = 0; i < 8; i++) dst[i] = fr[i] + ar[i];
    }
    __syncthreads();

    // --- phase 1: h1^T = W1rel^T * xin^T, in-place relu(c1 + F + A) into hfa ---
    #pragma unroll
    for (int ct = 0; ct < 8; ct++) {
        int p = ct * 16 + l15;
        half8 bx = *(const half8*)&xinL[p * 40 + g * 8];
        f32x4 z = {0.f, 0.f, 0.f, 0.f};
        f32x4 c1a = __builtin_amdgcn_mfma_f32_16x16x32_f16(a1[0], bx, z, 0, 0, 0);
        f32x4 c1b = __builtin_amdgcn_mfma_f32_16x16x32_f16(a1[1], bx, z, 0, 0, 0);
        #pragma unroll
        for (int rt = 0; rt < 2; rt++) {
            int ch0 = 32 * w + 16 * rt + g * 4;
            half4* hp = (half4*)&hfa[p * 136 + ch0];
            half4 bias = *hp;
            f32x4 cc = rt ? c1b : c1a;
            half4 hv;
            #pragma unroll
            for (int r = 0; r < 4; r++) {
                float s = cc[r] + (float)bias[r];
                hv[r] = (_Float16)fmaxf(s, 0.f);
            }
            *hp = hv;
        }
    }
    __syncthreads();

    // --- phase 2: h2^T = W2^T * h1^T, fold max over pairs ---
    f32x4 c2[8][2];
    #pragma unroll
    for (int ct = 0; ct < 8; ct++)
        #pragma unroll
        for (int rt = 0; rt < 2; rt++) {
            f32x4 z = {0.f, 0.f, 0.f, 0.f};
            c2[ct][rt] = z;
        }
    #pragma unroll
    for (int kc = 0; kc < 4; kc++) {
        #pragma unroll
        for (int ct = 0; ct < 8; ct++) {
            half8 bx = *(const half8*)&hfa[(ct * 16 + l15) * 136 + kc * 32 + g * 8];
            c2[ct][0] = __builtin_amdgcn_mfma_f32_16x16x32_f16(a2[0][kc], bx, c2[ct][0], 0, 0, 0);
            c2[ct][1] = __builtin_amdgcn_mfma_f32_16x16x32_f16(a2[1][kc], bx, c2[ct][1], 0, 0, 0);
        }
    }
    float mx[2][4];
    #pragma unroll
    for (int rt = 0; rt < 2; rt++)
        #pragma unroll
        for (int r = 0; r < 4; r++) {
            mx[rt][r] = fmaxf(fmaxf(c2[0][rt][r], c2[1][rt][r]), fmaxf(c2[2][rt][r], c2[3][rt][r]));
            mx[rt][r] = fmaxf(mx[rt][r],
                        fmaxf(fmaxf(c2[4][rt][r], c2[5][rt][r]), fmaxf(c2[6][rt][r], c2[7][rt][r])));
        }

    #pragma unroll
    for (int rt = 0; rt < 2; rt++)
        #pragma unroll
        for (int r = 0; r < 4; r++) {
            float v = mx[rt][r];
            #pragma unroll
            for (int off = 1; off < 16; off <<= 1)
                v = fmaxf(v, __shfl_xor(v, off));
            if (l15 == 0) {
                int ch = 32 * w + 16 * rt + g * 4 + r;
                atomicMax(&gmax[b * TOKC + ch], fkey(v));
            }
        }
}

// ---------------- final tiny MLP ----------------
__global__ __launch_bounds__(128) void k_final(const unsigned int* __restrict__ gmax,
                                               const float* __restrict__ b2,
                                               const float* __restrict__ W3,
                                               const float* __restrict__ b3,
                                               const float* __restrict__ W4,
                                               const float* __restrict__ b4,
                                               float* __restrict__ out) {
    __shared__ float gl[128], sl[128];
    int b = blockIdx.x, c = threadIdx.x;
    gl[c] = funkey(gmax[b * TOKC + c]) + b2[c];
    __syncthreads();
    float s = b3[c];
    for (int k = 0; k < 128; k++) s += gl[k] * W3[k * TOKC + c];
    sl[c] = fmaxf(s, 0.f);
    __syncthreads();
    float o = b4[c];
    for (int k = 0; k < 128; k++) o += sl[k] * W4[k * TOKC + c];
    out[b * TOKC + c] = o;
}

extern "C" void kernel_launch(void* const* d_in, const int* in_sizes, int n_in,
                              void* d_out, int out_size, void* d_ws, size_t ws_size,
                              hipStream_t stream) {
    const float* xyz  = (const float*)d_in[0];
    const float* feat = (const float*)d_in[1];
    const float* W1   = (const float*)d_in[2];
    const float* b1   = (const float*)d_in[3];
    const float* W2   = (const float*)d_in[4];
    const float* b2   = (const float*)d_in[5];
    const float* W3   = (const float*)d_in[6];
    const float* b3   = (const float*)d_in[7];
    const float* W4   = (const float*)d_in[8];
    const float* b4   = (const float*)d_in[9];

    char* ws = (char*)d_ws;
    int*          idxw = (int*)ws;
    _Float16*     Fh   = (_Float16*)(ws + OFF_FH);
    _Float16*     Ah   = (_Float16*)(ws + OFF_AH);
    unsigned int* gmax = (unsigned int*)(ws + OFF_GMAX);

    (void)hipMemsetAsync(gmax, 0, BATCH * TOKC * sizeof(unsigned int), stream);
    // blocks 0..2047: ball query (4 waves x 1 point); blocks 2048..2559: MFMA prep (16 points)
    k_pre<<<dim3(2560), dim3(256), 0, stream>>>(xyz, feat, W1, b1, idxw, Fh, Ah);
    k_main<<<dim3(BATCH * (NPTS / 4)), dim3(256), 0, stream>>>(xyz, W1, W2, idxw, Fh, Ah, gmax);
    k_final<<<dim3(BATCH), dim3(128), 0, stream>>>(gmax, b2, W3, b3, W4, b4, (float*)d_out);
}

// Round 7
// 147.737 us; speedup vs baseline: 1.6647x; 1.6647x over previous
//
#include <hip/hip_runtime.h>
#include <stdint.h>

#define BATCH 2
#define NPTS  4096
#define KNBR  32
#define TOKC  128

typedef _Float16 half8 __attribute__((ext_vector_type(8)));
typedef _Float16 half4 __attribute__((ext_vector_type(4)));
typedef float    f32x4 __attribute__((ext_vector_type(4)));

// ---------------- workspace layout (bytes) ----------------
// idx  : int      [2*4096*32] @ 0       (1 MB)
// Fh   : _Float16 [2*4096*128]@ 1 MB    (2 MB)
// Ah   : _Float16 [2*4096*128]@ 3 MB    (2 MB)
// gmax : uint     [256] + cnt uint @ 5 MB
// W1F  : _Float16 [8*512]  @ 5MB+2048   (8 KB)   A-frag-ordered W1 rows 64..90 (zero-padded to K=32)
// W2F  : _Float16 [32*512] @ 5MB+10240  (32 KB)  A-frag-ordered W2
#define OFF_FH   (1u << 20)
#define OFF_AH   (3u << 20)
#define OFF_GMAX (5u << 20)
#define OFF_W1F  ((5u << 20) + 2048)
#define OFF_W2F  ((5u << 20) + 10240)

__device__ __forceinline__ unsigned int fkey(float f) {
    unsigned int u = __float_as_uint(f);
    return (u & 0x80000000u) ? ~u : (u | 0x80000000u);
}
__device__ __forceinline__ float funkey(unsigned int k) {
    return __uint_as_float((k & 0x80000000u) ? (k ^ 0x80000000u) : ~k);
}

// ---------------- pass 1: blocks 0..2047 ball-query; 2048..2087 weight repack + init ----------------
__global__ __launch_bounds__(256) void k_pre(const float* __restrict__ xyz,
                                             const float* __restrict__ W1,
                                             const float* __restrict__ W2,
                                             int* __restrict__ oidx,
                                             _Float16* __restrict__ W1F,
                                             _Float16* __restrict__ W2F,
                                             unsigned int* __restrict__ gmax) {
    const int t = threadIdx.x;
    if (blockIdx.x >= 2048) {
        int f = blockIdx.x - 2048;          // 0..39
        if (f == 0) {                        // init gmax (256) + block counter
            if (t < 256) gmax[t] = 0u;
            if (t == 0) gmax[256] = 0u;
        }
        // repack one 512-half fragment: elem e -> lane=e>>3, j=e&7
        #pragma unroll
        for (int s = 0; s < 2; s++) {
            int e = t + s * 256;
            int lane = e >> 3, j = e & 7;
            int l15 = lane & 15, g = lane >> 4;
            if (f < 8) {                     // W1rel: ch tile f, K=32 (rows 27..31 zero)
                int k = g * 8 + j;
                int c = f * 16 + l15;
                float val = (k < 27) ? W1[(64 + k) * TOKC + c] : 0.f;
                W1F[f * 512 + e] = (_Float16)val;
            } else {                         // W2: frag (ct,kc)
                int f2 = f - 8;
                int ct = f2 >> 2, kc = f2 & 3;
                int k = kc * 32 + g * 8 + j;
                int c = ct * 16 + l15;
                W2F[f2 * 512 + e] = (_Float16)W2[k * TOKC + c];
            }
        }
        return;
    }
    // ---- ball query: one wave per point, next-chunk prefetch (bit-exact vs numpy) ----
    const int w = t >> 6, lane = t & 63;
    int wave = blockIdx.x * 4 + w;
    int b = wave >> 12;
    int n = wave & (NPTS - 1);
    const float* xb = xyz + (size_t)b * NPTS * 3;
    float cx = xb[n * 3 + 0], cy = xb[n * 3 + 1], cz = xb[n * 3 + 2];
    const float R2 = 0.0256f;
    int cnt = 0;
    int first = 0;
    int* out = oidx + (size_t)wave * KNBR;
    float px = xb[lane * 3 + 0], py = xb[lane * 3 + 1], pz = xb[lane * 3 + 2];
    for (int base = 0; base < NPTS; base += 64) {
        #pragma clang fp contract(off)
        float dx = px - cx, dy = py - cy, dz = pz - cz;
        float d2 = (dx * dx + dy * dy) + dz * dz;   // same order as numpy, no fma
        bool hit = d2 <= R2;
        int jn = ((base + 64) & (NPTS - 1)) + lane;
        float nx = xb[jn * 3 + 0], ny = xb[jn * 3 + 1], nz = xb[jn * 3 + 2];
        unsigned long long m = __ballot(hit);
        if (cnt == 0 && m) first = base + (int)__builtin_ctzll(m);
        if (hit) {
            int pos = cnt + (int)__popcll(m & ((1ull << lane) - 1ull));
            if (pos < KNBR) out[pos] = base + lane;
        }
        cnt += (int)__popcll(m);
        if (cnt >= KNBR) break;
        px = nx; py = ny; pz = nz;
    }
    if (lane >= cnt && lane < KNBR) out[lane] = first;
}

// ---------------- pass 2: precompute F[j], A[n] via MFMA ----------------
__global__ __launch_bounds__(256) void k_prep(const float* __restrict__ xyz,
                                              const float* __restrict__ feat,
                                              const float* __restrict__ W1,
                                              const float* __restrict__ b1,
                                              _Float16* __restrict__ Fh,
                                              _Float16* __restrict__ Ah) {
    __shared__ __align__(16) _Float16 inL[16][168];   // k: 0..63 feat, 64..159 abs-pe, +8 pad
    const int t = threadIdx.x;
    const int w = t >> 6, lane = t & 63;
    const int l15 = lane & 15, g = lane >> 4;
    const int g0 = blockIdx.x * 16;

    half8 af[2][2];
    half8 ap[2][3];
    float4 b1v[2];
    #pragma unroll
    for (int rt = 0; rt < 2; rt++) {
        int c = 32 * w + 16 * rt + l15;
        #pragma unroll
        for (int kc = 0; kc < 2; kc++)
            #pragma unroll
            for (int j = 0; j < 8; j++)
                af[rt][kc][j] = (_Float16)W1[(kc * 32 + g * 8 + j) * TOKC + c];
        #pragma unroll
        for (int kc = 0; kc < 3; kc++)
            #pragma unroll
            for (int j = 0; j < 8; j++)
                ap[rt][kc][j] = (_Float16)W1[(91 + kc * 32 + g * 8 + j) * TOKC + c];
        b1v[rt] = *(const float4*)&b1[32 * w + 16 * rt + g * 4];
    }

    {
        float4 v = ((const float4*)(feat + (size_t)g0 * 64))[t];
        half4 hv = {(_Float16)v.x, (_Float16)v.y, (_Float16)v.z, (_Float16)v.w};
        *(half4*)&inL[t >> 4][(t & 15) * 4] = hv;
    }
    {
        int p = t >> 4, v0 = (t & 15) * 6;
        const float* xp = xyz + (size_t)(g0 + p) * 3;
        #pragma unroll
        for (int u = 0; u < 6; u++) {
            int d = v0 + u;
            int a = d >> 5, i = d & 31, fi = i & 15;
            float fr = __expf(-0.6140226914650789f * (float)fi);  // ln(1e4)/15
            float ang = xp[a] * fr;
            inL[p][64 + d] = (_Float16)((i < 16) ? __sinf(ang) : __cosf(ang));
        }
    }
    __syncthreads();

    f32x4 cF[2], cA[2];
    #pragma unroll
    for (int rt = 0; rt < 2; rt++) { f32x4 z = {0.f, 0.f, 0.f, 0.f}; cF[rt] = z; cA[rt] = z; }
    #pragma unroll
    for (int kc = 0; kc < 2; kc++) {
        half8 bx = *(const half8*)&inL[l15][kc * 32 + g * 8];
        cF[0] = __builtin_amdgcn_mfma_f32_16x16x32_f16(af[0][kc], bx, cF[0], 0, 0, 0);
        cF[1] = __builtin_amdgcn_mfma_f32_16x16x32_f16(af[1][kc], bx, cF[1], 0, 0, 0);
    }
    #pragma unroll
    for (int kc = 0; kc < 3; kc++) {
        half8 bx = *(const half8*)&inL[l15][64 + kc * 32 + g * 8];
        cA[0] = __builtin_amdgcn_mfma_f32_16x16x32_f16(ap[0][kc], bx, cA[0], 0, 0, 0);
        cA[1] = __builtin_amdgcn_mfma_f32_16x16x32_f16(ap[1][kc], bx, cA[1], 0, 0, 0);
    }

    size_t pbase = ((size_t)g0 + l15) * TOKC;
    #pragma unroll
    for (int rt = 0; rt < 2; rt++) {
        int ch0 = 32 * w + 16 * rt + g * 4;
        half4 fv, av;
        #pragma unroll
        for (int r = 0; r < 4; r++) {
            fv[r] = (_Float16)cF[rt][r];
            av[r] = (_Float16)(cA[rt][r] + b1v[rt][r]);
        }
        *(half4*)&Fh[pbase + ch0] = fv;
        *(half4*)&Ah[pbase + ch0] = av;
    }
}

// ---------------- main: 512 persistent blocks x 4 tiles; coalesced frag weights; fused final MLP ----------------
__global__ __launch_bounds__(256, 3) void k_main(const float* __restrict__ xyz,
                                                 const int* __restrict__ idxw,
                                                 const _Float16* __restrict__ Fh,
                                                 const _Float16* __restrict__ Ah,
                                                 const _Float16* __restrict__ W1F,
                                                 const _Float16* __restrict__ W2F,
                                                 unsigned int* __restrict__ gmax,
                                                 const float* __restrict__ b2,
                                                 const float* __restrict__ W3,
                                                 const float* __restrict__ b3,
                                                 const float* __restrict__ W4,
                                                 const float* __restrict__ b4,
                                                 float* __restrict__ outp) {
    __shared__ __align__(16) _Float16 xinL[128 * 40];   // [pair][k32+pad8]
    __shared__ __align__(16) _Float16 hfa[128 * 136];   // [pair][ch128+pad8]
    __shared__ __align__(16) _Float16 arowL[512];
    __shared__ int jidxL[128];
    __shared__ unsigned int lastFlag;

    const int t = threadIdx.x;
    const int w = t >> 6, lane = t & 63;
    const int l15 = lane & 15, g = lane >> 4;
    const int b = blockIdx.x >> 8;
    const int pbase = (blockIdx.x & 255) * 16;
    const float* xb = xyz + (size_t)b * NPTS * 3;

    // --- coalesced persistent A-fragments (16B/lane from frag-ordered buffers) ---
    half8 a1[2];
    half8 a2[2][4];
    #pragma unroll
    for (int rt = 0; rt < 2; rt++) {
        a1[rt] = *(const half8*)&W1F[(2 * w + rt) * 512 + lane * 8];
        #pragma unroll
        for (int kc = 0; kc < 4; kc++)
            a2[rt][kc] = *(const half8*)&W2F[(((2 * w + rt) * 4 + kc)) * 512 + lane * 8];
    }

    float mx[2][4];
    #pragma unroll
    for (int rt = 0; rt < 2; rt++)
        #pragma unroll
        for (int r = 0; r < 4; r++) mx[rt][r] = -1e30f;

    const float FR[4] = {1.f, 0.0464158883f, 0.00215443469f, 1e-4f};

    // prefetch tile 0's idx + A rows into registers
    int jreg = 0;
    ushort ar0, ar1;
    {
        const size_t gq = (size_t)b * NPTS + pbase;
        if (t < 128) jreg = idxw[gq * KNBR + t];
        const ushort* Ain = (const ushort*)(Ah + gq * TOKC);
        ar0 = Ain[t]; ar1 = Ain[t + 256];
    }

    for (int it = 0; it < 4; it++) {
        const int n0 = pbase + it * 4;
        const size_t gp0 = (size_t)b * NPTS + n0;

        if (t < 128) jidxL[t] = jreg;
        ((ushort*)arowL)[t]       = ar0;
        ((ushort*)arowL)[t + 256] = ar1;
        __syncthreads();

        // issue next tile's prefetch immediately (completes during this tile's compute)
        if (it < 3) {
            const size_t gq = gp0 + 4;
            if (t < 128) jreg = idxw[gq * KNBR + t];
            const ushort* Ain = (const ushort*)(Ah + gq * TOKC);
            ar0 = Ain[t]; ar1 = Ain[t + 256];
        }

        // --- staging: all 256 threads; thread handles pair p=t>>1, half hh=t&1 ---
        {
            int p = t >> 1, hh = t & 1;
            int n = n0 + (p >> 5), j = jidxL[p];
            // Fh gather first (latency overlaps trig)
            const half8* frp = (const half8*)(Fh + ((size_t)b * NPTS + j) * TOKC + hh * 64);
            half8 fb[8];
            #pragma unroll
            for (int i = 0; i < 8; i++) fb[i] = frp[i];

            float rx = xb[j * 3 + 0] - xb[n * 3 + 0];
            float ry = xb[j * 3 + 1] - xb[n * 3 + 1];
            float rz = xb[j * 3 + 2] - xb[n * 3 + 2];
            float v[16];
            if (hh == 0) {       // dims 0..15: rel, sin/cos(rx), sin(ry), cos(ry,f0)
                v[0] = rx; v[1] = ry; v[2] = rz;
                #pragma unroll
                for (int fi = 0; fi < 4; fi++) {
                    float ang = rx * FR[fi];
                    v[3 + fi] = __sinf(ang);
                    v[7 + fi] = __cosf(ang);
                }
                #pragma unroll
                for (int fi = 0; fi < 4; fi++) v[11 + fi] = __sinf(ry * FR[fi]);
                v[15] = __cosf(ry * FR[0]);
            } else {             // dims 16..31: cos(ry,f1..3), sin/cos(rz), zeros
                #pragma unroll
                for (int fi = 1; fi < 4; fi++) v[fi - 1] = __cosf(ry * FR[fi]);
                #pragma unroll
                for (int fi = 0; fi < 4; fi++) {
                    float ang = rz * FR[fi];
                    v[3 + fi] = __sinf(ang);
                    v[7 + fi] = __cosf(ang);
                }
                #pragma unroll
                for (int i = 11; i < 16; i++) v[i] = 0.f;
            }
            half8 h0, h1;
            #pragma unroll
            for (int i = 0; i < 8; i++) { h0[i] = (_Float16)v[i]; h1[i] = (_Float16)v[8 + i]; }
            *(half8*)&xinL[p * 40 + hh * 16]     = h0;
            *(half8*)&xinL[p * 40 + hh * 16 + 8] = h1;

            const half8* arp = (const half8*)(arowL + (p >> 5) * TOKC + hh * 64);
            half8* dst = (half8*)(hfa + p * 136 + hh * 64);
            #pragma unroll
            for (int i = 0; i < 8; i++) dst[i] = fb[i] + arp[i];
        }
        __syncthreads();

        // --- phase 1: h1^T = W1rel^T * xin^T, in-place relu(c1 + F + A) into hfa ---
        #pragma unroll
        for (int ct = 0; ct < 8; ct++) {
            int p = ct * 16 + l15;
            half8 bx = *(const half8*)&xinL[p * 40 + g * 8];
            f32x4 z = {0.f, 0.f, 0.f, 0.f};
            f32x4 c1a = __builtin_amdgcn_mfma_f32_16x16x32_f16(a1[0], bx, z, 0, 0, 0);
            f32x4 c1b = __builtin_amdgcn_mfma_f32_16x16x32_f16(a1[1], bx, z, 0, 0, 0);
            #pragma unroll
            for (int rt = 0; rt < 2; rt++) {
                int ch0 = 32 * w + 16 * rt + g * 4;
                half4* hp = (half4*)&hfa[p * 136 + ch0];
                half4 bias = *hp;
                f32x4 cc = rt ? c1b : c1a;
                half4 hv;
                #pragma unroll
                for (int r = 0; r < 4; r++) {
                    float s = cc[r] + (float)bias[r];
                    hv[r] = (_Float16)fmaxf(s, 0.f);
                }
                *hp = hv;
            }
        }
        __syncthreads();

        // --- phase 2: h2^T = W2^T * h1^T, fold max ---
        f32x4 c2[8][2];
        #pragma unroll
        for (int ct = 0; ct < 8; ct++)
            #pragma unroll
            for (int rt = 0; rt < 2; rt++) {
                f32x4 z = {0.f, 0.f, 0.f, 0.f};
                c2[ct][rt] = z;
            }
        #pragma unroll
        for (int kc = 0; kc < 4; kc++) {
            #pragma unroll
            for (int ct = 0; ct < 8; ct++) {
                half8 bx = *(const half8*)&hfa[(ct * 16 + l15) * 136 + kc * 32 + g * 8];
                c2[ct][0] = __builtin_amdgcn_mfma_f32_16x16x32_f16(a2[0][kc], bx, c2[ct][0], 0, 0, 0);
                c2[ct][1] = __builtin_amdgcn_mfma_f32_16x16x32_f16(a2[1][kc], bx, c2[ct][1], 0, 0, 0);
            }
        }
        #pragma unroll
        for (int ct = 0; ct < 8; ct++)
            #pragma unroll
            for (int rt = 0; rt < 2; rt++)
                #pragma unroll
                for (int r = 0; r < 4; r++)
                    mx[rt][r] = fmaxf(mx[rt][r], c2[ct][rt][r]);
        __syncthreads();
    }

    #pragma unroll
    for (int rt = 0; rt < 2; rt++)
        #pragma unroll
        for (int r = 0; r < 4; r++) {
            float v = mx[rt][r];
            #pragma unroll
            for (int off = 1; off < 16; off <<= 1)
                v = fmaxf(v, __shfl_xor(v, off));
            if (l15 == 0) {
                int ch = 32 * w + 16 * rt + g * 4 + r;
                atomicMax(&gmax[b * TOKC + ch], fkey(v));
            }
        }

    // --- last-block-done: run the tiny final MLP here (saves a launch) ---
    if (t == 0) {
        __threadfence();
        unsigned int v = atomicAdd(&gmax[256], 1u);
        lastFlag = (v == 511u) ? 1u : 0u;
    }
    __syncthreads();
    if (lastFlag) {
        float* gl = (float*)xinL;          // reuse LDS: [2][128] + [2][128]
        float* sl = gl + 256;
        int bb = t >> 7, c = t & 127;
        unsigned int key = atomicOr(&gmax[bb * TOKC + c], 0u);   // device-coherent read
        gl[t] = funkey(key) + b2[c];
        __syncthreads();
        float s = b3[c];
        for (int k = 0; k < 128; k++) s += gl[bb * 128 + k] * W3[k * TOKC + c];
        sl[t] = fmaxf(s, 0.f);
        __syncthreads();
        float o = b4[c];
        for (int k = 0; k < 128; k++) o += sl[bb * 128 + k] * W4[k * TOKC + c];
        outp[t] = o;
    }
}

extern "C" void kernel_launch(void* const* d_in, const int* in_sizes, int n_in,
                              void* d_out, int out_size, void* d_ws, size_t ws_size,
                              hipStream_t stream) {
    const float* xyz  = (const float*)d_in[0];
    const float* feat = (const float*)d_in[1];
    const float* W1   = (const float*)d_in[2];
    const float* b1   = (const float*)d_in[3];
    const float* W2   = (const float*)d_in[4];
    const float* b2   = (const float*)d_in[5];
    const float* W3   = (const float*)d_in[6];
    const float* b3   = (const float*)d_in[7];
    const float* W4   = (const float*)d_in[8];
    const float* b4   = (const float*)d_in[9];

    char* ws = (char*)d_ws;
    int*          idxw = (int*)ws;
    _Float16*     Fh   = (_Float16*)(ws + OFF_FH);
    _Float16*     Ah   = (_Float16*)(ws + OFF_AH);
    unsigned int* gmax = (unsigned int*)(ws + OFF_GMAX);
    _Float16*     W1F  = (_Float16*)(ws + OFF_W1F);
    _Float16*     W2F  = (_Float16*)(ws + OFF_W2F);

    // L1: ball query (2048 blocks) + weight repack & init (40 blocks)
    k_pre<<<dim3(2088), dim3(256), 0, stream>>>(xyz, W1, W2, idxw, W1F, W2F, gmax);
    // L2: F/A precompute (MFMA)
    k_prep<<<dim3((BATCH * NPTS) / 16), dim3(256), 0, stream>>>(xyz, feat, W1, b1, Fh, Ah);
    // L3: main MLP + pooling + fused final MLP
    k_main<<<dim3(512), dim3(256), 0, stream>>>(xyz, idxw, Fh, Ah, W1F, W2F, gmax,
                                                b2, W3, b3, W4, b4, (float*)d_out);
}